// Round 6
// baseline (206.014 us; speedup 1.0000x reference)
//
#include <hip/hip_runtime.h>
#include <hip/hip_bf16.h>

// ConvexReLUCNN: B=512, C=3, H=W=64, KERNEL=3
//   K=27, L=62*62=3844, M=512, O=10
#define M_NEUR 512
#define ODIM   10
#define HO     62
#define LDIM   3844
#define CHW    12288
#define BATCH  512
#define KO     270
#define KOP    272                    // ko padded to 4*68
#define NPART  4                      // m-split partials
#define TPSTR  ((size_t)KO * LDIM)    // per-partial stride (elements)

// ---------------------------------------------------------------------------
// K0: pdP[m][ko] = v[m][ko] - w[m][ko]  (ko = k*10+o), zero-pad ko 270..271.
// ---------------------------------------------------------------------------
__global__ __launch_bounds__(256)
void pd_kernel(const float* __restrict__ v, const float* __restrict__ w,
               float* __restrict__ pdP) {
    int idx = blockIdx.x * 256 + threadIdx.x;
    if (idx >= M_NEUR * KOP) return;
    int m  = idx / KOP;
    int ko = idx - m * KOP;
    pdP[idx] = (ko < KO) ? (v[m * KO + ko] - w[m * KO + ko]) : 0.f;
}

// ---------------------------------------------------------------------------
// K1: Tp[mc][ko][n] (bf16) = sum_{m in chunk mc} pdP[m][ko] * G[m][n]
// Wave = 256 n (lane*4 float4) x 4 ko x 128 m. Block = 4 waves (4 ko-tiles).
// Grid 1088 = 8 xcd x 8 x 17; all 17 blocks sharing a G-panel on one XCD.
// 8-deep explicit register prefetch: 16 VMEM loads in flight per wave so the
// ~200cyc L2 latency hides under 256 cyc of FMA per chunk (fixes VGPR=32 /
// one-pair-in-flight serialization seen in round 5).
// ---------------------------------------------------------------------------
__global__ __launch_bounds__(256, 4)
void t_gemm_kernel(const float* __restrict__ G,
                   const float* __restrict__ pdP,
                   __hip_bfloat16* __restrict__ Tp) {
    const int bid  = blockIdx.x;
    const int xcd  = bid & 7;
    const int s    = bid >> 3;            // 0..135
    const int q    = s / 17;              // 0..7
    const int r    = s - q * 17;          // 0..16
    const int grp  = xcd + 8 * q;         // 0..63
    const int tile = grp >> 2;            // n-tile 0..15 (256 n each)
    const int mc   = grp & 3;             // m-chunk 0..3 (128 m each)
    const int wv   = threadIdx.x >> 6;    // 0..3
    const int lane = threadIdx.x & 63;
    const int jt   = 4 * r + wv;          // ko-tile 0..67
    const int ko0  = jt * 4;
    const int m0   = mc * 128;

    const int nb   = tile * 256 + lane * 4;
    const bool nok = (nb < LDIM);
    const int nbc  = nok ? nb : 0;

    const float4* Gp = reinterpret_cast<const float4*>(G + (size_t)m0 * LDIM + nbc);
    const float4* Pp = reinterpret_cast<const float4*>(pdP + (size_t)m0 * KOP + ko0);
    const int GS4 = LDIM / 4;   // 961
    const int PS4 = KOP / 4;    // 68

    float acc[4][4];
#pragma unroll
    for (int j = 0; j < 4; ++j)
#pragma unroll
        for (int nn = 0; nn < 4; ++nn) acc[j][nn] = 0.f;

#define FMA16(gv, pv)                                              \
    do {                                                           \
        acc[0][0] += (pv).x * (gv).x;  acc[0][1] += (pv).x * (gv).y; \
        acc[0][2] += (pv).x * (gv).z;  acc[0][3] += (pv).x * (gv).w; \
        acc[1][0] += (pv).y * (gv).x;  acc[1][1] += (pv).y * (gv).y; \
        acc[1][2] += (pv).y * (gv).z;  acc[1][3] += (pv).y * (gv).w; \
        acc[2][0] += (pv).z * (gv).x;  acc[2][1] += (pv).z * (gv).y; \
        acc[2][2] += (pv).z * (gv).z;  acc[2][3] += (pv).z * (gv).w; \
        acc[3][0] += (pv).w * (gv).x;  acc[3][1] += (pv).w * (gv).y; \
        acc[3][2] += (pv).w * (gv).z;  acc[3][3] += (pv).w * (gv).w; \
    } while (0)

    float4 gr[8], pr[8];
#pragma unroll
    for (int u = 0; u < 8; ++u) {
        gr[u] = Gp[(size_t)u * GS4];
        pr[u] = Pp[(size_t)u * PS4];
    }

#pragma unroll 1
    for (int mi = 0; mi < 120; mi += 8) {
#pragma unroll
        for (int u = 0; u < 8; ++u) {
            float4 gv = gr[u];
            float4 pv = pr[u];
            gr[u] = Gp[(size_t)(mi + 8 + u) * GS4];
            pr[u] = Pp[(size_t)(mi + 8 + u) * PS4];
            FMA16(gv, pv);
        }
    }
#pragma unroll
    for (int u = 0; u < 8; ++u)
        FMA16(gr[u], pr[u]);
#undef FMA16

    if (nok) {
        __hip_bfloat16* tb = Tp + (size_t)mc * TPSTR;
#pragma unroll
        for (int j = 0; j < 4; ++j) {
            int ko = ko0 + j;
            if (ko < KO) {
                __hip_bfloat162 lo, hi;
                lo.x = __float2bfloat16(acc[j][0]);
                lo.y = __float2bfloat16(acc[j][1]);
                hi.x = __float2bfloat16(acc[j][2]);
                hi.y = __float2bfloat16(acc[j][3]);
                __hip_bfloat162* dst =
                    reinterpret_cast<__hip_bfloat162*>(&tb[(size_t)ko * LDIM + nb]);
                dst[0] = lo;
                dst[1] = hi;
            }
        }
    }
}

// ---------------------------------------------------------------------------
// K2: fold 4 bf16 partials (ko, pix) -> S[o][c*4096 + h*64 + w] (fp32)
// One thread per output element (122880 threads).
// ---------------------------------------------------------------------------
__global__ __launch_bounds__(256)
void fold_kernel(const __hip_bfloat16* __restrict__ Tp, float* __restrict__ S) {
    int idx = blockIdx.x * 256 + threadIdx.x;   // o*CHW + chw
    if (idx >= ODIM * CHW) return;
    int o   = idx / CHW;
    int chw = idx - o * CHW;
    int c = chw >> 12;
    int h = (chw >> 6) & 63;
    int w = chw & 63;

    float s = 0.f;
    for (int i = 0; i < 3; ++i) {
        int pi = h - i;
        if ((unsigned)pi >= HO) continue;
        for (int j = 0; j < 3; ++j) {
            int pj = w - j;
            if ((unsigned)pj >= HO) continue;
            int ko  = (c * 9 + i * 3 + j) * ODIM + o;
            size_t off = (size_t)ko * LDIM + pi * HO + pj;
#pragma unroll
            for (int p = 0; p < NPART; ++p)
                s += __bfloat162float(Tp[(size_t)p * TPSTR + off]);
        }
    }
    S[idx] = s;
}

// ---------------------------------------------------------------------------
// K3: out[b][o] = sum_chw x[b][chw] * S[o][chw]; 2 images/block, 256 blocks.
// ---------------------------------------------------------------------------
__global__ __launch_bounds__(256)
void out_gemm_kernel(const float* __restrict__ X,
                     const float* __restrict__ S,
                     float* __restrict__ out) {
    const int b0  = blockIdx.x * 2;
    const int tid = threadIdx.x;
    const int NV  = CHW / 4;   // 3072
    const float4* X0 = reinterpret_cast<const float4*>(X) + (size_t)b0 * NV;
    const float4* X1 = X0 + NV;
    const float4* S4 = reinterpret_cast<const float4*>(S);

    float acc0[ODIM], acc1[ODIM];
#pragma unroll
    for (int o = 0; o < ODIM; ++o) { acc0[o] = 0.f; acc1[o] = 0.f; }

    for (int i = tid; i < NV; i += 256) {
        float4 a = X0[i];
        float4 b = X1[i];
#pragma unroll
        for (int o = 0; o < ODIM; ++o) {
            float4 sv = S4[(size_t)o * NV + i];
            acc0[o] += a.x * sv.x + a.y * sv.y + a.z * sv.z + a.w * sv.w;
            acc1[o] += b.x * sv.x + b.y * sv.y + b.z * sv.z + b.w * sv.w;
        }
    }

#pragma unroll
    for (int o = 0; o < ODIM; ++o) {
        float s0 = acc0[o], s1 = acc1[o];
        for (int off = 32; off > 0; off >>= 1) {
            s0 += __shfl_down(s0, off, 64);
            s1 += __shfl_down(s1, off, 64);
        }
        acc0[o] = s0; acc1[o] = s1;
    }

    __shared__ float red[4][2 * ODIM];
    int wave = tid >> 6;
    int lane = tid & 63;
    if (lane == 0) {
#pragma unroll
        for (int o = 0; o < ODIM; ++o) {
            red[wave][o] = acc0[o];
            red[wave][ODIM + o] = acc1[o];
        }
    }
    __syncthreads();
    if (tid < 2 * ODIM) {
        float tsum = red[0][tid] + red[1][tid] + red[2][tid] + red[3][tid];
        int bt = tid / ODIM;
        int o  = tid - bt * ODIM;
        out[(size_t)(b0 + bt) * ODIM + o] = tsum;
    }
}

extern "C" void kernel_launch(void* const* d_in, const int* in_sizes, int n_in,
                              void* d_out, int out_size, void* d_ws, size_t ws_size,
                              hipStream_t stream) {
    const float* x = (const float*)d_in[0];   // (512, 3, 64, 64)
    const float* G = (const float*)d_in[1];   // (512, 3844)
    const float* v = (const float*)d_in[2];   // (512, 27, 10)
    const float* w = (const float*)d_in[3];   // (512, 27, 10)
    float* out = (float*)d_out;               // (512, 10)

    __hip_bfloat16* Tp = (__hip_bfloat16*)d_ws;            // 4*270*3844*2B = 8.3 MB
    float* S   = (float*)(Tp + (size_t)NPART * TPSTR);     // 10*12288 f = 0.49 MB
    float* pdP = S + (size_t)ODIM * CHW;                   // 512*272 f = 0.56 MB

    pd_kernel<<<(M_NEUR * KOP + 255) / 256, 256, 0, stream>>>(v, w, pdP);

    t_gemm_kernel<<<1088, 256, 0, stream>>>(G, pdP, Tp);

    fold_kernel<<<(ODIM * CHW + 255) / 256, 256, 0, stream>>>(Tp, S);

    out_gemm_kernel<<<BATCH / 2, 256, 0, stream>>>(x, S, out);
}

// Round 7
// 51.908 us; speedup vs baseline: 3.9688x; 3.9688x over previous
//
#include <hip/hip_runtime.h>
#include <hip/hip_bf16.h>

// ConvexReLUCNN: B=512, C=3, H=W=64, KERNEL=3
//   K=27, L=62*62=3844, M=512, O=10
#define M_NEUR 512
#define ODIM   10
#define HO     62
#define LDIM   3844
#define CHW    12288
#define BATCH  512
#define KO     270
#define KOP    272                    // ko padded to 4*68
#define NPART  8                      // m-split partials (64 m each)
#define TPSTR  ((size_t)KO * LDIM)    // per-partial stride (elements)

// ---------------------------------------------------------------------------
// K0: pdP[m][ko] = v[m][ko] - w[m][ko]  (ko = k*10+o), zero-pad ko 270..271.
// ---------------------------------------------------------------------------
__global__ __launch_bounds__(256)
void pd_kernel(const float* __restrict__ v, const float* __restrict__ w,
               float* __restrict__ pdP) {
    int idx = blockIdx.x * 256 + threadIdx.x;
    if (idx >= M_NEUR * KOP) return;
    int m  = idx / KOP;
    int ko = idx - m * KOP;
    pdP[idx] = (ko < KO) ? (v[m * KO + ko] - w[m * KO + ko]) : 0.f;
}

// ---------------------------------------------------------------------------
// K1: Tp[mch][ko][n] (bf16) = sum_{m in chunk} pdP[m][ko] * G[m][n]
// Grid 512 = (ntile 0..15) x (kob 0..3) x (mch 0..7), with mch = bid&7 so
// each XCD reads only its 64-row G slice (984 KB, L2-resident, HBM once).
// Block 256 thr = 4 waves; wave w handles kos kob*68 + w*17 .. +16.
// Per m-iter: 1 coalesced G float4 load + 17 LDS floats (wave-uniform
// ds_read_b128, compiler-pipelined) -> 68 FMAs. acc = 17 float4 in VGPRs.
// No register rotation arrays (round-6 scratch-spill lesson).
// ---------------------------------------------------------------------------
__global__ __launch_bounds__(256, 2)
void t_gemm_kernel(const float* __restrict__ G,
                   const float* __restrict__ pdP,
                   __hip_bfloat16* __restrict__ Tp) {
    const int bid   = blockIdx.x;
    const int mch   = bid & 7;           // m-chunk == XCD slot
    const int rest  = bid >> 3;          // 0..63
    const int kob   = rest & 3;          // ko-block (68 kos)
    const int ntile = rest >> 2;         // n-tile (256 n)
    const int m0    = mch * 64;

    // pd slice for this (mch, kob): 64 m x 68 ko, laid out [m][wave*20 + s]
    // (pad 17->20 so every wave's base is 16B-aligned for ds_read_b128).
    __shared__ float pdL[64 * 80];
    for (int t = threadIdx.x; t < 64 * 68; t += 256) {
        int r  = t / 68;
        int ko = t - r * 68;
        int wv = ko / 17;
        int s  = ko - wv * 17;
        pdL[r * 80 + wv * 20 + s] = pdP[(size_t)(m0 + r) * KOP + kob * 68 + ko];
    }
    __syncthreads();

    const int wave = threadIdx.x >> 6;
    const int lane = threadIdx.x & 63;
    const int nb   = ntile * 256 + lane * 4;
    const bool nok = (nb + 3 < LDIM);
    const int nbc  = nok ? nb : 0;

    const float* lb  = &pdL[wave * 20];
    const float4* Gp = reinterpret_cast<const float4*>(G + (size_t)m0 * LDIM + nbc);
    const int GS4 = LDIM / 4;   // 961

    float4 acc[17];
#pragma unroll
    for (int s = 0; s < 17; ++s) acc[s] = make_float4(0.f, 0.f, 0.f, 0.f);

#pragma unroll 2
    for (int mi = 0; mi < 64; ++mi) {
        float4 gv = Gp[(size_t)mi * GS4];
        const float* p = lb + mi * 80;    // wave-uniform LDS row
#pragma unroll
        for (int s = 0; s < 17; ++s) {
            float pv = p[s];
            acc[s].x += pv * gv.x;
            acc[s].y += pv * gv.y;
            acc[s].z += pv * gv.z;
            acc[s].w += pv * gv.w;
        }
    }

    if (nok) {
        __hip_bfloat16* tb = Tp + (size_t)mch * TPSTR;
        const int koBase = kob * 68 + wave * 17;
#pragma unroll
        for (int s = 0; s < 17; ++s) {
            int ko = koBase + s;
            if (ko < KO) {
                union { __hip_bfloat162 h[2]; uint2 u; } pk;
                pk.h[0].x = __float2bfloat16(acc[s].x);
                pk.h[0].y = __float2bfloat16(acc[s].y);
                pk.h[1].x = __float2bfloat16(acc[s].z);
                pk.h[1].y = __float2bfloat16(acc[s].w);
                *reinterpret_cast<uint2*>(&tb[(size_t)ko * LDIM + nb]) = pk.u;
            }
        }
    }
}

// ---------------------------------------------------------------------------
// K2: fold 8 bf16 partials (ko, pix) -> S[o][c*4096 + h*64 + w] (fp32)
// One thread per output element (122880 threads).
// ---------------------------------------------------------------------------
__global__ __launch_bounds__(256)
void fold_kernel(const __hip_bfloat16* __restrict__ Tp, float* __restrict__ S) {
    int idx = blockIdx.x * 256 + threadIdx.x;   // o*CHW + chw
    if (idx >= ODIM * CHW) return;
    int o   = idx / CHW;
    int chw = idx - o * CHW;
    int c = chw >> 12;
    int h = (chw >> 6) & 63;
    int w = chw & 63;

    float s = 0.f;
    for (int i = 0; i < 3; ++i) {
        int pi = h - i;
        if ((unsigned)pi >= HO) continue;
        for (int j = 0; j < 3; ++j) {
            int pj = w - j;
            if ((unsigned)pj >= HO) continue;
            int ko  = (c * 9 + i * 3 + j) * ODIM + o;
            size_t off = (size_t)ko * LDIM + pi * HO + pj;
#pragma unroll
            for (int p = 0; p < NPART; ++p)
                s += __bfloat162float(Tp[(size_t)p * TPSTR + off]);
        }
    }
    S[idx] = s;
}

// ---------------------------------------------------------------------------
// K3: out[b][o] = sum_chw x[b][chw] * S[o][chw]; 2 images/block, 256 blocks.
// ---------------------------------------------------------------------------
__global__ __launch_bounds__(256)
void out_gemm_kernel(const float* __restrict__ X,
                     const float* __restrict__ S,
                     float* __restrict__ out) {
    const int b0  = blockIdx.x * 2;
    const int tid = threadIdx.x;
    const int NV  = CHW / 4;   // 3072
    const float4* X0 = reinterpret_cast<const float4*>(X) + (size_t)b0 * NV;
    const float4* X1 = X0 + NV;
    const float4* S4 = reinterpret_cast<const float4*>(S);

    float acc0[ODIM], acc1[ODIM];
#pragma unroll
    for (int o = 0; o < ODIM; ++o) { acc0[o] = 0.f; acc1[o] = 0.f; }

    for (int i = tid; i < NV; i += 256) {
        float4 a = X0[i];
        float4 b = X1[i];
#pragma unroll
        for (int o = 0; o < ODIM; ++o) {
            float4 sv = S4[(size_t)o * NV + i];
            acc0[o] += a.x * sv.x + a.y * sv.y + a.z * sv.z + a.w * sv.w;
            acc1[o] += b.x * sv.x + b.y * sv.y + b.z * sv.z + b.w * sv.w;
        }
    }

#pragma unroll
    for (int o = 0; o < ODIM; ++o) {
        float s0 = acc0[o], s1 = acc1[o];
        for (int off = 32; off > 0; off >>= 1) {
            s0 += __shfl_down(s0, off, 64);
            s1 += __shfl_down(s1, off, 64);
        }
        acc0[o] = s0; acc1[o] = s1;
    }

    __shared__ float red[4][2 * ODIM];
    int wave = tid >> 6;
    int lane = tid & 63;
    if (lane == 0) {
#pragma unroll
        for (int o = 0; o < ODIM; ++o) {
            red[wave][o] = acc0[o];
            red[wave][ODIM + o] = acc1[o];
        }
    }
    __syncthreads();
    if (tid < 2 * ODIM) {
        float tsum = red[0][tid] + red[1][tid] + red[2][tid] + red[3][tid];
        int bt = tid / ODIM;
        int o  = tid - bt * ODIM;
        out[(size_t)(b0 + bt) * ODIM + o] = tsum;
    }
}

extern "C" void kernel_launch(void* const* d_in, const int* in_sizes, int n_in,
                              void* d_out, int out_size, void* d_ws, size_t ws_size,
                              hipStream_t stream) {
    const float* x = (const float*)d_in[0];   // (512, 3, 64, 64)
    const float* G = (const float*)d_in[1];   // (512, 3844)
    const float* v = (const float*)d_in[2];   // (512, 27, 10)
    const float* w = (const float*)d_in[3];   // (512, 27, 10)
    float* out = (float*)d_out;               // (512, 10)

    __hip_bfloat16* Tp = (__hip_bfloat16*)d_ws;            // 8*270*3844*2B = 16.6 MB
    float* S   = (float*)(Tp + (size_t)NPART * TPSTR);     // 10*12288 f = 0.49 MB
    float* pdP = S + (size_t)ODIM * CHW;                   // 512*272 f = 0.56 MB

    pd_kernel<<<(M_NEUR * KOP + 255) / 256, 256, 0, stream>>>(v, w, pdP);

    t_gemm_kernel<<<512, 256, 0, stream>>>(G, pdP, Tp);

    fold_kernel<<<(ODIM * CHW + 255) / 256, 256, 0, stream>>>(Tp, S);

    out_gemm_kernel<<<BATCH / 2, 256, 0, stream>>>(x, S, out);
}